// Round 3
// baseline (6303.830 us; speedup 1.0000x reference)
//
#include <hip/hip_runtime.h>
#include <hip/hip_cooperative_groups.h>

typedef _Float16 f16;
typedef _Float16 f16x4 __attribute__((ext_vector_type(4)));
typedef _Float16 f16x8 __attribute__((ext_vector_type(8)));
typedef float    f32x4 __attribute__((ext_vector_type(4)));

#define S_   5
#define B_   32
#define T_   25
#define TM   24            // T-1 steps per sentence
#define H_   1024
#define E_   512
#define V_   32000
#define G3   (3*H_)        // 3072
#define M_ALL (S_*TM*B_)   // 3840 rows, ordered m = (s*TM + t)*B_ + b
#define NSTEP (S_*TM)      // 120 sequential steps per layer

// ---------------- fp32 -> fp16 convert (vectorized) ----------------
__global__ __launch_bounds__(256) void k_cvt(const float* __restrict__ src,
                                             f16* __restrict__ dst, int n4) {
  int i = blockIdx.x * 256 + threadIdx.x;
  if (i >= n4) return;
  float4 v = ((const float4*)src)[i];
  f16x4 o = {(f16)v.x, (f16)v.y, (f16)v.z, (f16)v.w};
  ((f16x4*)dst)[i] = o;
}

// ---------------- embed gather -> x16 (m-major = (s,t,b)) ----------------
__global__ __launch_bounds__(128) void k_gather(const int* __restrict__ ids,
                                                const float* __restrict__ embed,
                                                f16* __restrict__ x) {
  int m = blockIdx.x;                       // 0..3839
  int s = m / (TM * B_);
  int r = m % (TM * B_);
  int t = r >> 5, b = r & 31;
  int tok = ids[(s * B_ + b) * T_ + t];     // tokens[:, :-1]
  const float4* src = (const float4*)(embed + (size_t)tok * E_);
  f16x4* dst = (f16x4*)(x + (size_t)m * E_);
  int i = threadIdx.x;                      // 128 threads * 4 = 512 = E_
  float4 v = src[i];
  dst[i] = (f16x4){(f16)v.x, (f16)v.y, (f16)v.z, (f16)v.w};
}

// ---------------- TN GEMM: C[m][n] = sum_k A[m][k]*B[n][k] (+bias[n]) ----------------
// A: (M,K) f16 row-major, B: (N,K) f16 row-major, C fp32.
// remap=1: m=(s*TM+t)*B_+b is scattered to C[((s*B_+b)*TM+t)*N + n]  (logits layout)
__global__ __launch_bounds__(256) void k_gemm(const f16* __restrict__ A,
                                              const f16* __restrict__ B,
                                              const float* __restrict__ bias,
                                              float* __restrict__ C,
                                              int K, int N, int remap) {
  __shared__ __align__(16) f16 sA[128][40];   // +8 pad: 2-way max bank aliasing
  __shared__ __align__(16) f16 sB[128][40];
  const int m0 = blockIdx.x * 128, n0 = blockIdx.y * 128;
  const int tid = threadIdx.x, wave = tid >> 6, lane = tid & 63;
  const int l16 = lane & 15, lq = lane >> 4;
  const int wr = (wave & 1) * 64, wc = (wave >> 1) * 64;
  const int rS = tid >> 2, cS = (tid & 3) * 8;
  f32x4 acc[4][4] = {};
  for (int k0 = 0; k0 < K; k0 += 32) {
    *(f16x8*)&sA[rS][cS]    = *(const f16x8*)&A[(size_t)(m0 + rS) * K + k0 + cS];
    *(f16x8*)&sA[rS + 64][cS] = *(const f16x8*)&A[(size_t)(m0 + rS + 64) * K + k0 + cS];
    *(f16x8*)&sB[rS][cS]    = *(const f16x8*)&B[(size_t)(n0 + rS) * K + k0 + cS];
    *(f16x8*)&sB[rS + 64][cS] = *(const f16x8*)&B[(size_t)(n0 + rS + 64) * K + k0 + cS];
    __syncthreads();
    f16x8 af[4], bf[4];
#pragma unroll
    for (int i = 0; i < 4; ++i) af[i] = *(const f16x8*)&sA[wr + i * 16 + l16][lq * 8];
#pragma unroll
    for (int j = 0; j < 4; ++j) bf[j] = *(const f16x8*)&sB[wc + j * 16 + l16][lq * 8];
#pragma unroll
    for (int i = 0; i < 4; ++i)
#pragma unroll
      for (int j = 0; j < 4; ++j)
        acc[i][j] = __builtin_amdgcn_mfma_f32_16x16x32_f16(af[i], bf[j], acc[i][j], 0, 0, 0);
    __syncthreads();
  }
#pragma unroll
  for (int i = 0; i < 4; ++i)
#pragma unroll
    for (int j = 0; j < 4; ++j)
#pragma unroll
      for (int e = 0; e < 4; ++e) {
        int rm = m0 + wr + i * 16 + lq * 4 + e;   // C/D: row=(lane>>4)*4+e, col=lane&15
        int cn = n0 + wc + j * 16 + l16;
        float v = acc[i][j][e];
        if (bias) v += bias[cn];
        size_t off;
        if (remap) {
          int s = rm / (TM * B_), rr = rm % (TM * B_), t = rr >> 5, b = rr & 31;
          off = (size_t)((s * B_ + b) * TM + t) * N + cn;
        } else {
          off = (size_t)rm * N + cn;
        }
        C[off] = v;
      }
}

// ---------------- fused 2-layer pipelined GRU recurrence (cooperative) ----------------
// 64 blocks x 256 threads. Blocks 0..31 = layer 0, blocks 32..63 = layer 1.
// Software pipeline: iteration u, layer 0 computes step g=u, layer 1 computes g=u-1.
// ONE grid barrier per iteration -> 121 barriers total (was 240).
// Layer-1 blocks compute gi1 = h0[g] @ W_ih1^T on the fly (h0 read from layer-0's
// f16 ping-pong: written at iter g, read at iter g+1, overwritten at iter g+2).
// State layout per layer (mirrors launcher): h32a,h32b,c32a,c32b | h16a,h16b,c16a,c16b
__global__ __launch_bounds__(256) void k_rec2(const f16* __restrict__ Whh0,
                                              const float* __restrict__ bhh0,
                                              const f16* __restrict__ Wih1,
                                              const f16* __restrict__ Whh1,
                                              const float* __restrict__ bih1,
                                              const float* __restrict__ bhh1,
                                              const float* __restrict__ gi,   // (M_ALL,3H) incl b_ih0
                                              const int* __restrict__ lens,   // (S,B)
                                              char* __restrict__ state,
                                              f16* __restrict__ h1all) {      // (M_ALL,H)
  __shared__ __align__(16) f16 shA[B_][H_ + 8];   // own-layer h_prev
  __shared__ __align__(16) f16 shB[B_][H_ + 8];   // layer-1 only: x1 = h0[g]
  cooperative_groups::grid_group grid = cooperative_groups::this_grid();
  const size_t F32SZ = (size_t)B_ * H_ * 4;
  const size_t F16SZ = (size_t)B_ * H_ * 2;
  const size_t LAYER = 4 * F32SZ + 4 * F16SZ;
  const int bid = blockIdx.x, role = bid >> 5, blk = bid & 31;
  const int tid = threadIdx.x, wave = tid >> 6, lane = tid & 63;
  const int l16 = lane & 15, lq = lane >> 4;
  const int rh = (wave >> 1) * 16, ch = (wave & 1) * 16;
  const int col = blk * 32 + ch + l16;        // this lane's D-col AND B-frag row

  char* base = state + (size_t)role * LAYER;
  float* h32a = (float*)(base);              float* h32b = (float*)(base + F32SZ);
  float* c32a = (float*)(base + 2 * F32SZ);  float* c32b = (float*)(base + 3 * F32SZ);
  f16* h16a = (f16*)(base + 4 * F32SZ);           f16* h16b = (f16*)(base + 4 * F32SZ + F16SZ);
  f16* c16a = (f16*)(base + 4 * F32SZ + 2*F16SZ); f16* c16b = (f16*)(base + 4 * F32SZ + 3*F16SZ);
  const f16* h16a0 = (const f16*)(state + 4 * F32SZ);           // layer-0 ping-pong (x1 source)
  const f16* h16b0 = (const f16*)(state + 4 * F32SZ + F16SZ);

  const f16* Whh = role ? Whh1 : Whh0;
  const float* bhh = role ? bhh1 : bhh0;
  const float b_r = bhh[col], b_z = bhh[H_ + col], b_n = bhh[2 * H_ + col];
  float bi_r = 0.f, bi_z = 0.f, bi_n = 0.f;
  if (role) { bi_r = bih1[col]; bi_z = bih1[H_ + col]; bi_n = bih1[2 * H_ + col]; }
  const f16* wR = Whh + (size_t)col * H_ + lq * 8;
  const f16* wZ = Whh + (size_t)(H_ + col) * H_ + lq * 8;
  const f16* wN = Whh + (size_t)(2 * H_ + col) * H_ + lq * 8;
  const f16* uR = Wih1 + (size_t)col * H_ + lq * 8;
  const f16* uZ = Wih1 + (size_t)(H_ + col) * H_ + lq * 8;
  const f16* uN = Wih1 + (size_t)(2 * H_ + col) * H_ + lq * 8;

  for (int u = 0; u <= NSTEP; ++u) {
    const int g = u - role;
    if (g >= 0 && g < NSTEP) {
      const int s = g / TM, t = g % TM;
      const f16*  hsrc   = (t == 0) ? ((s & 1) ? c16b : c16a)
                                    : ((g & 1) ? h16b : h16a);
      const float* hold32 = (t == 0) ? ((s & 1) ? c32b : c32a)
                                     : ((g & 1) ? h32b : h32a);
      f16*   h16w = (((g + 1) & 1) ? h16b : h16a);
      float* h32w = (((g + 1) & 1) ? h32b : h32a);
      f16*   c16w = (((s + 1) & 1) ? c16b : c16a);
      float* c32w = (((s + 1) & 1) ? c32b : c32a);
      // stage own-layer h_prev (32 x 1024 f16) into LDS
      for (int i = tid; i < B_ * (H_ / 8); i += 256) {
        int r = i >> 7, c = (i & 127) * 8;
        *(f16x8*)&shA[r][c] = *(const f16x8*)&hsrc[r * H_ + c];
      }
      if (role) {
        // stage x1 = h0[g] from layer-0's write-buffer of parity (g+1)&1
        const f16* xsrc = (((g + 1) & 1) ? h16b0 : h16a0);
        for (int i = tid; i < B_ * (H_ / 8); i += 256) {
          int r = i >> 7, c = (i & 127) * 8;
          *(f16x8*)&shB[r][c] = *(const f16x8*)&xsrc[r * H_ + c];
        }
      }
      __syncthreads();
      const int mbase = g * B_;
      // prefetch (independent of matmul) so loads overlap MFMA
      float gir[4], giz[4], gin[4], hprev[4];
#pragma unroll
      for (int e = 0; e < 4; ++e) {
        int row = rh + lq * 4 + e;
        hprev[e] = hold32[row * H_ + col];
        if (!role) {
          size_t gx = (size_t)(mbase + row) * G3 + col;
          gir[e] = gi[gx];
          giz[e] = gi[gx + H_];
          gin[e] = gi[gx + 2 * H_];
        }
      }
      f32x4 ar = {}, az = {}, an = {};          // recurrent part (both roles)
      f32x4 xr = {}, xz = {}, xn = {};          // layer-1 input part (gi1)
      const f16* aP = &shA[rh + l16][lq * 8];   // A-frag: m=lane&15, k=quad*8+j
      const f16* xP = &shB[rh + l16][lq * 8];
      if (!role) {
#pragma unroll 4
        for (int kc = 0; kc < H_ / 32; ++kc) {
          f16x8 a = *(const f16x8*)(aP + kc * 32);
          ar = __builtin_amdgcn_mfma_f32_16x16x32_f16(a, *(const f16x8*)(wR + kc * 32), ar, 0, 0, 0);
          az = __builtin_amdgcn_mfma_f32_16x16x32_f16(a, *(const f16x8*)(wZ + kc * 32), az, 0, 0, 0);
          an = __builtin_amdgcn_mfma_f32_16x16x32_f16(a, *(const f16x8*)(wN + kc * 32), an, 0, 0, 0);
        }
      } else {
#pragma unroll 2
        for (int kc = 0; kc < H_ / 32; ++kc) {
          f16x8 a = *(const f16x8*)(aP + kc * 32);
          f16x8 x = *(const f16x8*)(xP + kc * 32);
          ar = __builtin_amdgcn_mfma_f32_16x16x32_f16(a, *(const f16x8*)(wR + kc * 32), ar, 0, 0, 0);
          az = __builtin_amdgcn_mfma_f32_16x16x32_f16(a, *(const f16x8*)(wZ + kc * 32), az, 0, 0, 0);
          an = __builtin_amdgcn_mfma_f32_16x16x32_f16(a, *(const f16x8*)(wN + kc * 32), an, 0, 0, 0);
          xr = __builtin_amdgcn_mfma_f32_16x16x32_f16(x, *(const f16x8*)(uR + kc * 32), xr, 0, 0, 0);
          xz = __builtin_amdgcn_mfma_f32_16x16x32_f16(x, *(const f16x8*)(uZ + kc * 32), xz, 0, 0, 0);
          xn = __builtin_amdgcn_mfma_f32_16x16x32_f16(x, *(const f16x8*)(uN + kc * 32), xn, 0, 0, 0);
        }
      }
#pragma unroll
      for (int e = 0; e < 4; ++e) {
        int row = rh + lq * 4 + e;
        float i_r, i_z, i_n;
        if (role) { i_r = xr[e] + bi_r; i_z = xz[e] + bi_z; i_n = xn[e] + bi_n; }
        else      { i_r = gir[e];       i_z = giz[e];       i_n = gin[e]; }
        float r = 1.f / (1.f + __expf(-(ar[e] + b_r + i_r)));
        float z = 1.f / (1.f + __expf(-(az[e] + b_z + i_z)));
        float x2 = 2.f * (i_n + r * (an[e] + b_n));
        float n = 1.f - 2.f / (__expf(x2) + 1.f);   // tanh, saturates safely
        float hv = (1.f - z) * n + z * hprev[e];
        f16 hf = (f16)hv;
        h32w[row * H_ + col] = hv;
        h16w[row * H_ + col] = hf;
        if (role) h1all[(size_t)(mbase + row) * H_ + col] = hf;
        int ib = lens[s * B_ + row] - 2;
        ib = ib < 0 ? 0 : (ib > TM - 1 ? TM - 1 : ib);
        if (t == ib) { c32w[row * H_ + col] = hv; c16w[row * H_ + col] = hf; }
      }
    }
    __threadfence();
    grid.sync();
    __threadfence();
  }
}

// ---------------- launcher ----------------
extern "C" void kernel_launch(void* const* d_in, const int* in_sizes, int n_in,
                              void* d_out, int out_size, void* d_ws, size_t ws_size,
                              hipStream_t stream) {
  const int*   ids   = (const int*)d_in[0];
  const int*   lens  = (const int*)d_in[1];
  const float* embed = (const float*)d_in[2];
  const float* Wih0  = (const float*)d_in[3];
  const float* Whh0  = (const float*)d_in[4];
  const float* bih0  = (const float*)d_in[5];
  const float* bhh0  = (const float*)d_in[6];
  const float* Wih1  = (const float*)d_in[7];
  const float* Whh1  = (const float*)d_in[8];
  const float* bih1  = (const float*)d_in[9];
  const float* bhh1  = (const float*)d_in[10];
  const float* Wout  = (const float*)d_in[11];
  float* out = (float*)d_out;

  char* w = (char*)d_ws;
  size_t off = 0;
  auto alloc = [&](size_t bytes) -> void* {
    void* p = w + off;
    off = (off + bytes + 255) & ~(size_t)255;
    return p;
  };
  f16*   Wih0h = (f16*)alloc((size_t)G3 * E_ * 2);
  f16*   Whh0h = (f16*)alloc((size_t)G3 * H_ * 2);
  f16*   Wih1h = (f16*)alloc((size_t)G3 * H_ * 2);
  f16*   Whh1h = (f16*)alloc((size_t)G3 * H_ * 2);
  f16*   Wouth = (f16*)alloc((size_t)V_ * H_ * 2);
  f16*   x16   = (f16*)alloc((size_t)M_ALL * E_ * 2);
  float* gib   = (float*)alloc((size_t)M_ALL * G3 * 4);   // gi0 only now
  f16*   h1all = (f16*)alloc((size_t)M_ALL * H_ * 2);
  const size_t F32SZ = (size_t)B_ * H_ * 4;   // 128 KB
  const size_t F16SZ = (size_t)B_ * H_ * 2;   //  64 KB
  const size_t LAYER = 4 * F32SZ + 4 * F16SZ; // h32a,h32b,c32a,c32b,h16a,h16b,c16a,c16b
  char* state = (char*)alloc(2 * LAYER);

  hipMemsetAsync(state, 0, 2 * LAYER, stream);   // zeroes initial h carry (h_init = 0)

  int n4;
  n4 = G3 * E_ / 4; k_cvt<<<(n4 + 255) / 256, 256, 0, stream>>>(Wih0, Wih0h, n4);
  n4 = G3 * H_ / 4; k_cvt<<<(n4 + 255) / 256, 256, 0, stream>>>(Whh0, Whh0h, n4);
                    k_cvt<<<(n4 + 255) / 256, 256, 0, stream>>>(Whh1, Whh1h, n4);
                    k_cvt<<<(n4 + 255) / 256, 256, 0, stream>>>(Wih1, Wih1h, n4);
  n4 = V_ * H_ / 4; k_cvt<<<(n4 + 255) / 256, 256, 0, stream>>>(Wout, Wouth, n4);
  k_gather<<<M_ALL, 128, 0, stream>>>(ids, embed, x16);

  // gi0 = x @ W_ih0^T + b_ih0
  k_gemm<<<dim3(M_ALL / 128, G3 / 128), 256, 0, stream>>>(x16, Wih0h, bih0, gib, E_, G3, 0);

  // fused pipelined 2-layer recurrence (gi1 computed in-kernel)
  {
    void* args[] = {(void*)&Whh0h, (void*)&bhh0, (void*)&Wih1h, (void*)&Whh1h,
                    (void*)&bih1, (void*)&bhh1, (void*)&gib, (void*)&lens,
                    (void*)&state, (void*)&h1all};
    hipLaunchCooperativeKernel((void*)k_rec2, dim3(64), dim3(256), args, 0, stream);
  }

  // logits = h1_all @ W_out^T, scattered to (s,b,t,v)
  k_gemm<<<dim3(M_ALL / 128, V_ / 128), 256, 0, stream>>>(h1all, Wouth, nullptr, out, H_, V_, 1);
}

// Round 4
// 5648.730 us; speedup vs baseline: 1.1160x; 1.1160x over previous
//
#include <hip/hip_runtime.h>
#include <hip/hip_cooperative_groups.h>

typedef _Float16 f16;
typedef _Float16 f16x4 __attribute__((ext_vector_type(4)));
typedef _Float16 f16x8 __attribute__((ext_vector_type(8)));
typedef float    f32x4 __attribute__((ext_vector_type(4)));

#define S_   5
#define B_   32
#define T_   25
#define TM   24            // T-1 steps per sentence
#define H_   1024
#define E_   512
#define V_   32000
#define G3   (3*H_)        // 3072
#define M_ALL (S_*TM*B_)   // 3840 rows, ordered m = (s*TM + t)*B_ + b
#define NSTEP (S_*TM)      // 120 sequential steps per layer
#define NBLK 64            // coop grid size

// ---- per-access agent-coherent ops (avoid cache-wide wbl2/inv of __threadfence) ----
__device__ __forceinline__ void st_f16_agent(f16* p, f16 v) {
  unsigned short u = *(unsigned short*)&v;
  __hip_atomic_store((unsigned short*)p, u, __ATOMIC_RELAXED, __HIP_MEMORY_SCOPE_AGENT);
}
__device__ __forceinline__ unsigned long long ld_u64_agent(const f16* p) {
  return __hip_atomic_load((const unsigned long long*)p, __ATOMIC_RELAXED, __HIP_MEMORY_SCOPE_AGENT);
}

// ---------------- fp32 -> fp16 convert (vectorized) ----------------
__global__ __launch_bounds__(256) void k_cvt(const float* __restrict__ src,
                                             f16* __restrict__ dst, int n4) {
  int i = blockIdx.x * 256 + threadIdx.x;
  if (i >= n4) return;
  float4 v = ((const float4*)src)[i];
  f16x4 o = {(f16)v.x, (f16)v.y, (f16)v.z, (f16)v.w};
  ((f16x4*)dst)[i] = o;
}

// ---------------- embed gather -> x16 (m-major = (s,t,b)) ----------------
__global__ __launch_bounds__(128) void k_gather(const int* __restrict__ ids,
                                                const float* __restrict__ embed,
                                                f16* __restrict__ x) {
  int m = blockIdx.x;                       // 0..3839
  int s = m / (TM * B_);
  int r = m % (TM * B_);
  int t = r >> 5, b = r & 31;
  int tok = ids[(s * B_ + b) * T_ + t];     // tokens[:, :-1]
  const float4* src = (const float4*)(embed + (size_t)tok * E_);
  f16x4* dst = (f16x4*)(x + (size_t)m * E_);
  int i = threadIdx.x;                      // 128 threads * 4 = 512 = E_
  float4 v = src[i];
  dst[i] = (f16x4){(f16)v.x, (f16)v.y, (f16)v.z, (f16)v.w};
}

// ---------------- TN GEMM: C[m][n] = sum_k A[m][k]*B[n][k] (+bias[n]) ----------------
// A: (M,K) f16 row-major, B: (N,K) f16 row-major, C fp32.
// remap=1: m=(s*TM+t)*B_+b is scattered to C[((s*B_+b)*TM+t)*N + n]  (logits layout)
__global__ __launch_bounds__(256) void k_gemm(const f16* __restrict__ A,
                                              const f16* __restrict__ B,
                                              const float* __restrict__ bias,
                                              float* __restrict__ C,
                                              int K, int N, int remap) {
  __shared__ __align__(16) f16 sA[128][40];   // +8 pad: 2-way max bank aliasing
  __shared__ __align__(16) f16 sB[128][40];
  const int m0 = blockIdx.x * 128, n0 = blockIdx.y * 128;
  const int tid = threadIdx.x, wave = tid >> 6, lane = tid & 63;
  const int l16 = lane & 15, lq = lane >> 4;
  const int wr = (wave & 1) * 64, wc = (wave >> 1) * 64;
  const int rS = tid >> 2, cS = (tid & 3) * 8;
  f32x4 acc[4][4] = {};
  for (int k0 = 0; k0 < K; k0 += 32) {
    *(f16x8*)&sA[rS][cS]    = *(const f16x8*)&A[(size_t)(m0 + rS) * K + k0 + cS];
    *(f16x8*)&sA[rS + 64][cS] = *(const f16x8*)&A[(size_t)(m0 + rS + 64) * K + k0 + cS];
    *(f16x8*)&sB[rS][cS]    = *(const f16x8*)&B[(size_t)(n0 + rS) * K + k0 + cS];
    *(f16x8*)&sB[rS + 64][cS] = *(const f16x8*)&B[(size_t)(n0 + rS + 64) * K + k0 + cS];
    __syncthreads();
    f16x8 af[4], bf[4];
#pragma unroll
    for (int i = 0; i < 4; ++i) af[i] = *(const f16x8*)&sA[wr + i * 16 + l16][lq * 8];
#pragma unroll
    for (int j = 0; j < 4; ++j) bf[j] = *(const f16x8*)&sB[wc + j * 16 + l16][lq * 8];
#pragma unroll
    for (int i = 0; i < 4; ++i)
#pragma unroll
      for (int j = 0; j < 4; ++j)
        acc[i][j] = __builtin_amdgcn_mfma_f32_16x16x32_f16(af[i], bf[j], acc[i][j], 0, 0, 0);
    __syncthreads();
  }
#pragma unroll
  for (int i = 0; i < 4; ++i)
#pragma unroll
    for (int j = 0; j < 4; ++j)
#pragma unroll
      for (int e = 0; e < 4; ++e) {
        int rm = m0 + wr + i * 16 + lq * 4 + e;   // C/D: row=(lane>>4)*4+e, col=lane&15
        int cn = n0 + wc + j * 16 + l16;
        float v = acc[i][j][e];
        if (bias) v += bias[cn];
        size_t off;
        if (remap) {
          int s = rm / (TM * B_), rr = rm % (TM * B_), t = rr >> 5, b = rr & 31;
          off = (size_t)((s * B_ + b) * TM + t) * N + cn;
        } else {
          off = (size_t)rm * N + cn;
        }
        C[off] = v;
      }
}

// ---------------- fused 2-layer pipelined GRU recurrence (cooperative) ----------------
// 64 blocks x 256 threads. Blocks 0..31 = layer 0, blocks 32..63 = layer 1.
// Iteration u: layer 0 computes step g=u, layer 1 computes g=u-1. 121 barriers.
// Barrier = hand-rolled monotonic counter (device-scope atomicAdd + relaxed spin):
// NO __threadfence / grid.sync -> L2 never invalidated -> weights stay L2-resident.
// Cross-block state (f16 h/c ping-pong) uses per-access agent-coherent ops instead;
// h32/c32 hprev are block-private (same block writes/reads its own 32 cols) -> plain.
__global__ __launch_bounds__(256) void k_rec2(const f16* __restrict__ Whh0,
                                              const float* __restrict__ bhh0,
                                              const f16* __restrict__ Wih1,
                                              const f16* __restrict__ Whh1,
                                              const float* __restrict__ bih1,
                                              const float* __restrict__ bhh1,
                                              const float* __restrict__ gi,   // (M_ALL,3H) incl b_ih0
                                              const int* __restrict__ lens,   // (S,B)
                                              char* __restrict__ state,
                                              unsigned* __restrict__ bar,
                                              f16* __restrict__ h1all) {      // (M_ALL,H)
  __shared__ __align__(16) f16 shA[B_][H_ + 8];   // own-layer h_prev
  __shared__ __align__(16) f16 shB[B_][H_ + 8];   // layer-1 only: x1 = h0[g]
  const size_t F32SZ = (size_t)B_ * H_ * 4;
  const size_t F16SZ = (size_t)B_ * H_ * 2;
  const size_t LAYER = 4 * F32SZ + 4 * F16SZ;
  const int bid = blockIdx.x, role = bid >> 5, blk = bid & 31;
  const int tid = threadIdx.x, wave = tid >> 6, lane = tid & 63;
  const int l16 = lane & 15, lq = lane >> 4;
  const int rh = (wave >> 1) * 16, ch = (wave & 1) * 16;
  const int col = blk * 32 + ch + l16;        // this lane's D-col AND B-frag row

  char* base = state + (size_t)role * LAYER;
  float* h32a = (float*)(base);              float* h32b = (float*)(base + F32SZ);
  float* c32a = (float*)(base + 2 * F32SZ);  float* c32b = (float*)(base + 3 * F32SZ);
  f16* h16a = (f16*)(base + 4 * F32SZ);           f16* h16b = (f16*)(base + 4 * F32SZ + F16SZ);
  f16* c16a = (f16*)(base + 4 * F32SZ + 2*F16SZ); f16* c16b = (f16*)(base + 4 * F32SZ + 3*F16SZ);
  const f16* h16a0 = (const f16*)(state + 4 * F32SZ);           // layer-0 ping-pong (x1 source)
  const f16* h16b0 = (const f16*)(state + 4 * F32SZ + F16SZ);

  const f16* Whh = role ? Whh1 : Whh0;
  const float* bhh = role ? bhh1 : bhh0;
  const float b_r = bhh[col], b_z = bhh[H_ + col], b_n = bhh[2 * H_ + col];
  float bi_r = 0.f, bi_z = 0.f, bi_n = 0.f;
  if (role) { bi_r = bih1[col]; bi_z = bih1[H_ + col]; bi_n = bih1[2 * H_ + col]; }
  const f16* wR = Whh + (size_t)col * H_ + lq * 8;
  const f16* wZ = Whh + (size_t)(H_ + col) * H_ + lq * 8;
  const f16* wN = Whh + (size_t)(2 * H_ + col) * H_ + lq * 8;
  const f16* uR = Wih1 + (size_t)col * H_ + lq * 8;
  const f16* uZ = Wih1 + (size_t)(H_ + col) * H_ + lq * 8;
  const f16* uN = Wih1 + (size_t)(2 * H_ + col) * H_ + lq * 8;

  for (int u = 0; u <= NSTEP; ++u) {
    const int g = u - role;
    if (g >= 0 && g < NSTEP) {
      const int s = g / TM, t = g % TM;
      const f16*  hsrc   = (t == 0) ? ((s & 1) ? c16b : c16a)
                                    : ((g & 1) ? h16b : h16a);
      const float* hold32 = (t == 0) ? ((s & 1) ? c32b : c32a)
                                     : ((g & 1) ? h32b : h32a);
      f16*   h16w = (((g + 1) & 1) ? h16b : h16a);
      float* h32w = (((g + 1) & 1) ? h32b : h32a);
      f16*   c16w = (((s + 1) & 1) ? c16b : c16a);
      float* c32w = (((s + 1) & 1) ? c32b : c32a);
      // stage own-layer h_prev (32 x 1024 f16) into LDS — agent-coherent 8B loads
      for (int i = tid; i < B_ * (H_ / 4); i += 256) {
        int r = i >> 8, c = (i & 255) * 4;          // H_/4 = 256 chunks per row
        unsigned long long v = ld_u64_agent(&hsrc[r * H_ + c]);
        *(unsigned long long*)&shA[r][c] = v;
      }
      if (role) {
        // stage x1 = h0[g] from layer-0's write-buffer of parity (g+1)&1
        const f16* xsrc = (((g + 1) & 1) ? h16b0 : h16a0);
        for (int i = tid; i < B_ * (H_ / 4); i += 256) {
          int r = i >> 8, c = (i & 255) * 4;
          unsigned long long v = ld_u64_agent(&xsrc[r * H_ + c]);
          *(unsigned long long*)&shB[r][c] = v;
        }
      }
      __syncthreads();
      const int mbase = g * B_;
      // prefetch (independent of matmul) so loads overlap MFMA
      float gir[4], giz[4], gin[4], hprev[4];
#pragma unroll
      for (int e = 0; e < 4; ++e) {
        int row = rh + lq * 4 + e;
        hprev[e] = hold32[row * H_ + col];
        if (!role) {
          size_t gx = (size_t)(mbase + row) * G3 + col;
          gir[e] = gi[gx];
          giz[e] = gi[gx + H_];
          gin[e] = gi[gx + 2 * H_];
        }
      }
      f32x4 ar = {}, az = {}, an = {};          // recurrent part (both roles)
      f32x4 xr = {}, xz = {}, xn = {};          // layer-1 input part (gi1)
      const f16* aP = &shA[rh + l16][lq * 8];   // A-frag: m=lane&15, k=quad*8+j
      const f16* xP = &shB[rh + l16][lq * 8];
      if (!role) {
#pragma unroll 4
        for (int kc = 0; kc < H_ / 32; ++kc) {
          f16x8 a = *(const f16x8*)(aP + kc * 32);
          ar = __builtin_amdgcn_mfma_f32_16x16x32_f16(a, *(const f16x8*)(wR + kc * 32), ar, 0, 0, 0);
          az = __builtin_amdgcn_mfma_f32_16x16x32_f16(a, *(const f16x8*)(wZ + kc * 32), az, 0, 0, 0);
          an = __builtin_amdgcn_mfma_f32_16x16x32_f16(a, *(const f16x8*)(wN + kc * 32), an, 0, 0, 0);
        }
      } else {
#pragma unroll 2
        for (int kc = 0; kc < H_ / 32; ++kc) {
          f16x8 a = *(const f16x8*)(aP + kc * 32);
          f16x8 x = *(const f16x8*)(xP + kc * 32);
          ar = __builtin_amdgcn_mfma_f32_16x16x32_f16(a, *(const f16x8*)(wR + kc * 32), ar, 0, 0, 0);
          az = __builtin_amdgcn_mfma_f32_16x16x32_f16(a, *(const f16x8*)(wZ + kc * 32), az, 0, 0, 0);
          an = __builtin_amdgcn_mfma_f32_16x16x32_f16(a, *(const f16x8*)(wN + kc * 32), an, 0, 0, 0);
          xr = __builtin_amdgcn_mfma_f32_16x16x32_f16(x, *(const f16x8*)(uR + kc * 32), xr, 0, 0, 0);
          xz = __builtin_amdgcn_mfma_f32_16x16x32_f16(x, *(const f16x8*)(uZ + kc * 32), xz, 0, 0, 0);
          xn = __builtin_amdgcn_mfma_f32_16x16x32_f16(x, *(const f16x8*)(uN + kc * 32), xn, 0, 0, 0);
        }
      }
#pragma unroll
      for (int e = 0; e < 4; ++e) {
        int row = rh + lq * 4 + e;
        float i_r, i_z, i_n;
        if (role) { i_r = xr[e] + bi_r; i_z = xz[e] + bi_z; i_n = xn[e] + bi_n; }
        else      { i_r = gir[e];       i_z = giz[e];       i_n = gin[e]; }
        float r = 1.f / (1.f + __expf(-(ar[e] + b_r + i_r)));
        float z = 1.f / (1.f + __expf(-(az[e] + b_z + i_z)));
        float x2 = 2.f * (i_n + r * (an[e] + b_n));
        float n = 1.f - 2.f / (__expf(x2) + 1.f);   // tanh, saturates safely
        float hv = (1.f - z) * n + z * hprev[e];
        f16 hf = (f16)hv;
        h32w[row * H_ + col] = hv;                       // block-private: plain
        st_f16_agent(&h16w[row * H_ + col], hf);         // cross-block: coherent
        if (role) h1all[(size_t)(mbase + row) * H_ + col] = hf;  // next-kernel only
        int ib = lens[s * B_ + row] - 2;
        ib = ib < 0 ? 0 : (ib > TM - 1 ? TM - 1 : ib);
        if (t == ib) {
          c32w[row * H_ + col] = hv;                     // block-private: plain
          st_f16_agent(&c16w[row * H_ + col], hf);       // cross-block: coherent
        }
      }
    }
    // ---- hand-rolled grid barrier: monotonic counter, no cache-wide fences ----
    __syncthreads();                 // drains vmcnt(0): all waves' stores visible-at-coherent-point
    if (tid == 0) {
      atomicAdd(bar, 1u);            // device-scope
      const unsigned tgt = (unsigned)(u + 1) * NBLK;
      while (__hip_atomic_load(bar, __ATOMIC_RELAXED, __HIP_MEMORY_SCOPE_AGENT) < tgt)
        __builtin_amdgcn_s_sleep(1);
    }
    __syncthreads();
  }
}

// ---------------- launcher ----------------
extern "C" void kernel_launch(void* const* d_in, const int* in_sizes, int n_in,
                              void* d_out, int out_size, void* d_ws, size_t ws_size,
                              hipStream_t stream) {
  const int*   ids   = (const int*)d_in[0];
  const int*   lens  = (const int*)d_in[1];
  const float* embed = (const float*)d_in[2];
  const float* Wih0  = (const float*)d_in[3];
  const float* Whh0  = (const float*)d_in[4];
  const float* bih0  = (const float*)d_in[5];
  const float* bhh0  = (const float*)d_in[6];
  const float* Wih1  = (const float*)d_in[7];
  const float* Whh1  = (const float*)d_in[8];
  const float* bih1  = (const float*)d_in[9];
  const float* bhh1  = (const float*)d_in[10];
  const float* Wout  = (const float*)d_in[11];
  float* out = (float*)d_out;

  char* w = (char*)d_ws;
  size_t off = 0;
  auto alloc = [&](size_t bytes) -> void* {
    void* p = w + off;
    off = (off + bytes + 255) & ~(size_t)255;
    return p;
  };
  f16*   Wih0h = (f16*)alloc((size_t)G3 * E_ * 2);
  f16*   Whh0h = (f16*)alloc((size_t)G3 * H_ * 2);
  f16*   Wih1h = (f16*)alloc((size_t)G3 * H_ * 2);
  f16*   Whh1h = (f16*)alloc((size_t)G3 * H_ * 2);
  f16*   Wouth = (f16*)alloc((size_t)V_ * H_ * 2);
  f16*   x16   = (f16*)alloc((size_t)M_ALL * E_ * 2);
  float* gib   = (float*)alloc((size_t)M_ALL * G3 * 4);   // gi0 only
  f16*   h1all = (f16*)alloc((size_t)M_ALL * H_ * 2);
  const size_t F32SZ = (size_t)B_ * H_ * 4;   // 128 KB
  const size_t F16SZ = (size_t)B_ * H_ * 2;   //  64 KB
  const size_t LAYER = 4 * F32SZ + 4 * F16SZ; // h32a,h32b,c32a,c32b,h16a,h16b,c16a,c16b
  char* state = (char*)alloc(2 * LAYER);
  unsigned* bar = (unsigned*)alloc(256);      // grid-barrier counter (contiguous after state)

  hipMemsetAsync(state, 0, 2 * LAYER + 256, stream);  // zero h carry + barrier counter

  int n4;
  n4 = G3 * E_ / 4; k_cvt<<<(n4 + 255) / 256, 256, 0, stream>>>(Wih0, Wih0h, n4);
  n4 = G3 * H_ / 4; k_cvt<<<(n4 + 255) / 256, 256, 0, stream>>>(Whh0, Whh0h, n4);
                    k_cvt<<<(n4 + 255) / 256, 256, 0, stream>>>(Whh1, Whh1h, n4);
                    k_cvt<<<(n4 + 255) / 256, 256, 0, stream>>>(Wih1, Wih1h, n4);
  n4 = V_ * H_ / 4; k_cvt<<<(n4 + 255) / 256, 256, 0, stream>>>(Wout, Wouth, n4);
  k_gather<<<M_ALL, 128, 0, stream>>>(ids, embed, x16);

  // gi0 = x @ W_ih0^T + b_ih0
  k_gemm<<<dim3(M_ALL / 128, G3 / 128), 256, 0, stream>>>(x16, Wih0h, bih0, gib, E_, G3, 0);

  // fused pipelined 2-layer recurrence (gi1 computed in-kernel)
  {
    void* args[] = {(void*)&Whh0h, (void*)&bhh0, (void*)&Wih1h, (void*)&Whh1h,
                    (void*)&bih1, (void*)&bhh1, (void*)&gib, (void*)&lens,
                    (void*)&state, (void*)&bar, (void*)&h1all};
    hipLaunchCooperativeKernel((void*)k_rec2, dim3(64), dim3(256), args, 0, stream);
  }

  // logits = h1_all @ W_out^T, scattered to (s,b,t,v)
  k_gemm<<<dim3(M_ALL / 128, V_ / 128), 256, 0, stream>>>(h1all, Wouth, nullptr, out, H_, V_, 1);
}